// Round 8
// baseline (1629.595 us; speedup 1.0000x reference)
//
#include <hip/hip_runtime.h>
#include <hip/hip_bf16.h>

typedef unsigned short u16;
typedef __attribute__((ext_vector_type(8))) short short8;
typedef __attribute__((ext_vector_type(4))) float f32x4;
typedef __attribute__((ext_vector_type(8))) unsigned short ushort8v;

#define NVOX 200000
#define NVP  200064
#define NOFF 27
#define NBLK 1563

__device__ __forceinline__ u16 f2bf(float f) {
    __hip_bfloat16 h = __float2bfloat16(f);
    return *reinterpret_cast<u16*>(&h);
}
__device__ __forceinline__ float bf2f(u16 u) {
    union { unsigned int i; float f; } v;
    v.i = ((unsigned int)u) << 16;
    return v.f;
}

// ---------------------------------------------------------------------------
// prep: cast x -> bf16; repack W1/W2 fragment-major; zero page.
// ---------------------------------------------------------------------------
__global__ __launch_bounds__(256) void prep_kernel(
    const float* __restrict__ x, const float* __restrict__ W1,
    const float* __restrict__ W2, u16* __restrict__ xb,
    u16* __restrict__ w1t, u16* __restrict__ w2t, float* __restrict__ zbuf)
{
    const int XV = NVOX * 96 / 4;     // 4,800,000 vec4 cast jobs
    const int WC = 62208;             // W chunk jobs per conv (27*36*64)
    int t = blockIdx.x * 256 + threadIdx.x;
    if (blockIdx.x == 0 && threadIdx.x < 64) zbuf[threadIdx.x] = 0.f;
    if (t < XV) {
        float4 v = *(const float4*)(x + (size_t)t * 4);
        ushort4 o;
        o.x = f2bf(v.x); o.y = f2bf(v.y); o.z = f2bf(v.z); o.w = f2bf(v.w);
        *(ushort4*)(xb + (size_t)t * 4) = o;
    } else if (t < XV + WC) {
        int j = t - XV;
        int lane = j & 63, rest = j >> 6;
        int nco = rest % 12, rest2 = rest / 12;
        int ks = rest2 % 3, off = rest2 / 3;
        int co = nco * 16 + (lane & 15);
        int kb = ks * 32 + (lane >> 4) * 8;
        const float* src = W1 + (size_t)off * 18432 + (size_t)kb * 192 + co;
        ushort8v ov;
#pragma unroll
        for (int jj = 0; jj < 8; ++jj) ov[jj] = f2bf(src[(size_t)jj * 192]);
        *(ushort8v*)(w1t + (size_t)j * 8) = ov;
    } else if (t < XV + 2 * WC) {
        int j = t - XV - WC;
        int lane = j & 63, rest = j >> 6;
        int nco = rest % 6, rest2 = rest / 6;
        int kk = rest2 % 6, off = rest2 / 6;
        int co = nco * 16 + (lane & 15);
        int kb = kk * 32 + (lane >> 4) * 8;
        const float* src = W2 + (size_t)off * 18432 + (size_t)kb * 96 + co;
        ushort8v ov;
#pragma unroll
        for (int jj = 0; jj < 8; ++jj) ov[jj] = f2bf(src[(size_t)jj * 96]);
        *(ushort8v*)(w2t + (size_t)j * 8) = ov;
    }
}

// ---------------------------------------------------------------------------
// lsrc precompute: lsrcG[off][row] = mask>0 ? idx : -1  (rows padded to NVP)
// ---------------------------------------------------------------------------
__global__ __launch_bounds__(256) void lsrc_kernel(
    const int* __restrict__ idxp, const int* __restrict__ mskp,
    int* __restrict__ lsrcG)
{
    int r = blockIdx.x * 256 + threadIdx.x;
    int o = blockIdx.y;
    if (r < NVP) {
        int v = -1;
        if (r < NVOX) {
            if (mskp[(size_t)o * NVOX + r] > 0) v = idxp[(size_t)o * NVOX + r];
        }
        lsrcG[(size_t)o * NVP + r] = v;
    }
}

// ---------------------------------------------------------------------------
// conv: explicit-GEMM sparse conv, bf16 MFMA, f32 accum.
//   Reg-staged A (global coalesced -> reg -> ds_write), LDS = 12 chunk-planes
//   x 520 dwords (pad makes ds_read banks uniform: (8K+12*lr) mod 32, wrap
//   == 0 mod 32 -> 2 lanes/bank, conflict-free).  3 buffers, 2-deep gather
//   pipeline with FIFO-clean issue order (W first -> counted vmcnt waits,
//   never vmcnt(0) in the loop; raw s_barrier).
//   Epilogue: fused BN partial sums + bf16 store.
// ---------------------------------------------------------------------------
template<int COUT, int WN, int HFDIV>
__global__ __launch_bounds__(512, 4) void conv_mfma(
    const u16* __restrict__ xb, const int* __restrict__ lsrcG,
    const u16* __restrict__ Wt, const float* __restrict__ zbuf,
    u16* __restrict__ hout, float* __restrict__ part)
{
    constexpr int CIN  = 96 * HFDIV;
    constexpr int WM   = 8 / WN;
    constexpr int FM   = 128 / (WM * 16);
    constexpr int FN   = COUT / (WN * 16);
    constexpr int NCO  = COUT / 16;
    constexpr int SG   = NOFF * HFDIV;     // K-steps (27 or 54)
    constexpr int PLN  = 520;              // dwords per plane (128*4 + 8 pad)
    constexpr int BUFD = 12 * PLN;         // 6240 dwords = 24960 B

    __shared__ unsigned int ldsA[3 * BUFD];   // 74880 B -> 2 blocks/CU

    const int tid  = threadIdx.x;
    const int row0 = blockIdx.x * 128;
    const int lane = tid & 63;
    const int wid  = tid >> 6;
    const int wm   = wid / WN;
    const int wn   = wid % WN;
    const int lr   = lane & 15;
    const int lk   = lane >> 4;

    // staging constants: job l = it*512+tid -> row r = l/12, chunk c = l%12
    int svOff[3], aOffU[3], wDw[3];
#pragma unroll
    for (int it = 0; it < 3; ++it) {
        int l = it * 512 + tid;
        int r = l / 12, c = l % 12;
        svOff[it] = row0 + r;
        aOffU[it] = c * 8;                       // u16 offset in source row
        int p = (c + r) % 12;                    // plane rotation
        wDw[it] = p * PLN + r * 4;               // dword offset in buffer
    }
    // read constants per m
    int rB4[FM], rm12[FM];
#pragma unroll
    for (int m = 0; m < FM; ++m) {
        int r = wm * (FM * 16) + m * 16 + lr;
        rB4[m]  = r * 4;
        rm12[m] = (lk + r) % 12;
    }
    const u16* wtw = Wt + (size_t)(wn * FN) * 512 + (size_t)lane * 8;

    f32x4 acc[FM][FN];
#pragma unroll
    for (int m = 0; m < FM; ++m)
#pragma unroll
        for (int n = 0; n < FN; ++n)
            acc[m][n] = (f32x4){0.f, 0.f, 0.f, 0.f};

    int sv[3];
    uint4 ar[3];
    auto svLoad = [&](int s) {
        int offIdx = (HFDIV == 1) ? s : (s >> 1);
        const int* base = lsrcG + (size_t)offIdx * NVP;
#pragma unroll
        for (int it = 0; it < 3; ++it) sv[it] = base[svOff[it]];
    };
    auto aIssue = [&](int s) {
        int hf = (HFDIV == 1) ? 0 : (s & 1);
#pragma unroll
        for (int it = 0; it < 3; ++it) {
            const u16* g = (sv[it] >= 0)
                ? (xb + (size_t)sv[it] * CIN + hf * 96 + aOffU[it])
                : ((const u16*)zbuf + aOffU[it]);
            ar[it] = *(const uint4*)g;
        }
    };
    auto aWrite = [&](int bsel) {
        unsigned int* b = ldsA + bsel * BUFD;
#pragma unroll
        for (int it = 0; it < 3; ++it)
            *(uint4*)(b + wDw[it]) = ar[it];
    };

    short8 wreg[3][FN];
    auto loadW = [&](int s) {
#pragma unroll
        for (int ks = 0; ks < 3; ++ks)
#pragma unroll
            for (int n = 0; n < FN; ++n)
                wreg[ks][n] = *(const short8*)(
                    wtw + ((size_t)(3 * s + ks) * NCO + n) * 512);
    };
    auto mfmaKs = [&](int ks, const unsigned int* abuf) {
#pragma unroll
        for (int m = 0; m < FM; ++m) {
            int p = rm12[m] + ks * 4;
            if (p >= 12) p -= 12;
            short8 af = *(const short8*)(abuf + p * PLN + rB4[m]);
#pragma unroll
            for (int n = 0; n < FN; ++n)
                acc[m][n] = __builtin_amdgcn_mfma_f32_16x16x32_bf16(
                    af, wreg[ks][n], acc[m][n], 0, 0, 0);
        }
    };

    // ---- prologue: stage A(0), A(1); preload sv(2) ----
    svLoad(0); aIssue(0); aWrite(0);
    svLoad(1); aIssue(1); aWrite(1);
    svLoad(2);
    __syncthreads();

    // ---- main loop: compute s from buf[s%3]; stage A(s+2); never drain ----
    int cur = 0, nxt2 = 2;
#pragma unroll 1
    for (int s = 0; s < SG; ++s) {
        loadW(s);                                   // FIFO oldest: 9 loads
        __builtin_amdgcn_sched_barrier(0);
        if (s + 2 < SG) aIssue(s + 2);              // 3 loads (stay in flight)
        if (s + 3 < SG) svLoad(s + 3);              // 3 loads (1.5-step cover)
        __builtin_amdgcn_sched_barrier(0);
        const unsigned int* abuf = ldsA + cur * BUFD;
        mfmaKs(0, abuf);                            // W-use: vmcnt<=6
        mfmaKs(1, abuf);
        __builtin_amdgcn_sched_barrier(0);
        if (s + 2 < SG) aWrite(nxt2);               // waits vmcnt<=3 (A regs)
        __builtin_amdgcn_sched_barrier(0);
        mfmaKs(2, abuf);
        __builtin_amdgcn_sched_barrier(0);
        __builtin_amdgcn_s_barrier();               // raw: no vmem drain
        __builtin_amdgcn_sched_barrier(0);
        cur  = (cur == 2)  ? 0 : cur + 1;
        nxt2 = (nxt2 == 2) ? 0 : nxt2 + 1;
    }

    // ---- fused BN statsA: per-block partial sum/sumsq per channel ----
    __syncthreads();
    float* smf = (float*)ldsA;             // overlay [WM][COUT][2]
#pragma unroll
    for (int n = 0; n < FN; ++n) {
        float s1 = 0.f, s2 = 0.f;
#pragma unroll
        for (int m = 0; m < FM; ++m)
#pragma unroll
            for (int q = 0; q < 4; ++q) {
                float v = acc[m][n][q];
                s1 += v; s2 += v * v;
            }
        s1 += __shfl_xor(s1, 16); s1 += __shfl_xor(s1, 32);
        s2 += __shfl_xor(s2, 16); s2 += __shfl_xor(s2, 32);
        if (lane < 16) {
            int col = wn * (FN * 16) + n * 16 + lr;
            smf[(wm * COUT + col) * 2 + 0] = s1;
            smf[(wm * COUT + col) * 2 + 1] = s2;
        }
    }
    __syncthreads();
    if (tid < 2 * COUT) {
        int z = tid / COUT, cc = tid % COUT;
        float v = 0.f;
#pragma unroll
        for (int w = 0; w < WM; ++w) v += smf[(w * COUT + cc) * 2 + z];
        part[(size_t)blockIdx.x * (2 * COUT) + z * COUT + cc] = v;
    }

    // ---- store h (bf16): D layout col=lane&15, row=(lane>>4)*4+q ----
#pragma unroll
    for (int m = 0; m < FM; ++m) {
#pragma unroll
        for (int q = 0; q < 4; ++q) {
            int row = row0 + wm * (FM * 16) + m * 16 + lk * 4 + q;
            if (row < NVOX) {
#pragma unroll
                for (int n = 0; n < FN; ++n) {
                    int col = wn * (FN * 16) + n * 16 + lr;
                    hout[(size_t)row * COUT + col] = f2bf(acc[m][n][q]);
                }
            }
        }
    }
}

// ---------------------------------------------------------------------------
// BN stats reduce: sum partials over NBLK blocks, emit scale/shift
// ---------------------------------------------------------------------------
template<int COUT>
__global__ __launch_bounds__(256) void bn_statsB(
    const float* __restrict__ part, const float* __restrict__ g,
    const float* __restrict__ bv, float* __restrict__ ss)
{
    const int c = blockIdx.x;
    const int t = threadIdx.x;
    float s1 = 0.f, s2 = 0.f;
    for (int b = t; b < NBLK; b += 256) {
        s1 += part[(size_t)b * 2 * COUT + c];
        s2 += part[(size_t)b * 2 * COUT + COUT + c];
    }
#pragma unroll
    for (int d = 1; d < 64; d <<= 1) {
        s1 += __shfl_xor(s1, d);
        s2 += __shfl_xor(s2, d);
    }
    __shared__ float rs[8];
    int w = t >> 6;
    if ((t & 63) == 0) { rs[w] = s1; rs[4 + w] = s2; }
    __syncthreads();
    if (t == 0) {
        s1 = rs[0] + rs[1] + rs[2] + rs[3];
        s2 = rs[4] + rs[5] + rs[6] + rs[7];
        float mu  = s1 * (1.0f / NVOX);
        float var = s2 * (1.0f / NVOX) - mu * mu;
        float sc  = g[c] * rsqrtf(var + 1e-5f);
        ss[c] = sc;
        ss[COUT + c] = bv[c] - mu * sc;
    }
}

// ---------------------------------------------------------------------------
// apply BN + ReLU in place (bf16), vec8
// ---------------------------------------------------------------------------
template<int COUT>
__global__ __launch_bounds__(256) void bn_apply_relu(
    u16* __restrict__ h, const float* __restrict__ ss)
{
    int t = blockIdx.x * 256 + threadIdx.x;   // < NVOX*COUT/8
    int c0 = (t * 8) % COUT;
    ushort8v v = *(ushort8v*)(h + (size_t)t * 8);
#pragma unroll
    for (int j = 0; j < 8; ++j) {
        float f = bf2f(v[j]);
        f = fmaxf(f * ss[c0 + j] + ss[COUT + c0 + j], 0.f);
        v[j] = f2bf(f);
    }
    *(ushort8v*)(h + (size_t)t * 8) = v;
}

// ---------------------------------------------------------------------------
// final: out = relu(scale2*h2 + shift2 + x), f32 out, vec8
// ---------------------------------------------------------------------------
__global__ __launch_bounds__(256) void final_kernel(
    const u16* __restrict__ h2, const float* __restrict__ x,
    const float* __restrict__ ss, float* __restrict__ out)
{
    int t = blockIdx.x * 256 + threadIdx.x;   // < NVOX*96/8
    int c0 = (t * 8) % 96;
    ushort8v v = *(const ushort8v*)(h2 + (size_t)t * 8);
    float4 x0 = *(const float4*)(x + (size_t)t * 8);
    float4 x1 = *(const float4*)(x + (size_t)t * 8 + 4);
    float xs[8] = {x0.x, x0.y, x0.z, x0.w, x1.x, x1.y, x1.z, x1.w};
    float o[8];
#pragma unroll
    for (int j = 0; j < 8; ++j) {
        float f = bf2f(v[j]) * ss[c0 + j] + ss[96 + c0 + j] + xs[j];
        o[j] = fmaxf(f, 0.f);
    }
    *(float4*)(out + (size_t)t * 8)     = (float4){o[0], o[1], o[2], o[3]};
    *(float4*)(out + (size_t)t * 8 + 4) = (float4){o[4], o[5], o[6], o[7]};
}

// ---------------------------------------------------------------------------
extern "C" void kernel_launch(void* const* d_in, const int* in_sizes, int n_in,
                              void* d_out, int out_size, void* d_ws, size_t ws_size,
                              hipStream_t stream)
{
    const float* x    = (const float*)d_in[0];
    const int*   idx  = (const int*)d_in[1];
    const int*   mask = (const int*)d_in[2];
    const float* W1   = (const float*)d_in[3];
    const float* g1   = (const float*)d_in[4];
    const float* b1   = (const float*)d_in[5];
    const float* W2   = (const float*)d_in[6];
    const float* g2   = (const float*)d_in[7];
    const float* b2   = (const float*)d_in[8];

    unsigned char* ws = (unsigned char*)d_ws;
    u16*  xb    = (u16*)ws;                          // 38,400,000 B
    u16*  w1t   = (u16*)(ws + 38400000);             //    995,328 B
    u16*  w2t   = (u16*)(ws + 39395328);             //    995,328 B
    u16*  h2    = (u16*)(ws + 40390656);             // 38,400,000 B
    float* part = (float*)(ws + 78790656);           //  2,400,768 B
    float* ss1  = (float*)(ws + 81191424);           //      1,536 B
    float* ss2  = (float*)(ws + 81192960);           //        768 B
    float* zbuf = (float*)(ws + 81193728);           //        256 B
    int*  lsrcG = (int*)(ws + 81193984);             // 21,606,912 B

    u16* h = (u16*)d_out;         // reuse d_out (76.8MB) as [N][192] bf16

    prep_kernel<<<19236, 256, 0, stream>>>(x, W1, W2, xb, w1t, w2t, zbuf);
    lsrc_kernel<<<dim3(782, 27), 256, 0, stream>>>(idx, mask, lsrcG);

    // conv1: COUT=192, 2m x 4n waves (FM=4, FN=3), K=96 per offset
    conv_mfma<192, 4, 1><<<NBLK, 512, 0, stream>>>(xb, lsrcG, w1t, zbuf, h, part);
    bn_statsB<192><<<192, 256, 0, stream>>>(part, g1, b1, ss1);
    bn_apply_relu<192><<<18750, 256, 0, stream>>>(h, ss1);

    // conv2: COUT=96, 4m x 2n waves (FM=2, FN=3), K=192 in two 96-phases
    conv_mfma<96, 2, 2><<<NBLK, 512, 0, stream>>>(h, lsrcG, w2t, zbuf, h2, part);
    bn_statsB<96><<<96, 256, 0, stream>>>(part, g2, b2, ss2);
    final_kernel<<<9375, 256, 0, stream>>>(h2, x, ss2, (float*)d_out);
}

// Round 9
// 725.457 us; speedup vs baseline: 2.2463x; 2.2463x over previous
//
#include <hip/hip_runtime.h>
#include <hip/hip_bf16.h>

typedef unsigned short u16;
typedef __attribute__((ext_vector_type(8))) short short8;
typedef __attribute__((ext_vector_type(4))) float f32x4;
typedef __attribute__((ext_vector_type(8))) unsigned short ushort8v;

#define NVOX 200000
#define NVP  200064
#define NOFF 27
#define NBLK 1563

__device__ __forceinline__ u16 f2bf(float f) {
    __hip_bfloat16 h = __float2bfloat16(f);
    return *reinterpret_cast<u16*>(&h);
}
__device__ __forceinline__ float bf2f(u16 u) {
    union { unsigned int i; float f; } v;
    v.i = ((unsigned int)u) << 16;
    return v.f;
}

#define GLOAD_LDS16(g, l)                                                     \
    __builtin_amdgcn_global_load_lds(                                         \
        (const __attribute__((address_space(1))) unsigned int*)(g),           \
        (__attribute__((address_space(3))) unsigned int*)(l), 16, 0, 0)

// compiler-proof loads (volatile asm: cannot be sunk/reordered/auto-waited)
__device__ __forceinline__ uint4 gld128(const u16* p) {
    uint4 r;
    asm volatile("global_load_dwordx4 %0, %1, off" : "=v"(r) : "v"(p) : "memory");
    return r;
}
__device__ __forceinline__ int gld32(const int* p) {
    int r;
    asm volatile("global_load_dword %0, %1, off" : "=v"(r) : "v"(p) : "memory");
    return r;
}
__device__ __forceinline__ uint4 dsr128(const u16* p) {
    uint4 r;
    asm volatile("ds_read_b128 %0, %1"
                 : "=v"(r)
                 : "v"((const __attribute__((address_space(3))) uint4*)p));
    return r;
}
__device__ __forceinline__ short8 as_s8(uint4 v) {
    union { uint4 u; short8 s; } c; c.u = v; return c.s;
}
#define S_WAIT_VM(n) asm volatile("s_waitcnt vmcnt(" #n ")" ::: "memory")
#define S_WAIT_LG(n) asm volatile("s_waitcnt lgkmcnt(" #n ")" ::: "memory")
#define SBAR0()      __builtin_amdgcn_sched_barrier(0)

// ---------------------------------------------------------------------------
// prep: cast x -> bf16; repack W1/W2 fragment-major; zero page.
// ---------------------------------------------------------------------------
__global__ __launch_bounds__(256) void prep_kernel(
    const float* __restrict__ x, const float* __restrict__ W1,
    const float* __restrict__ W2, u16* __restrict__ xb,
    u16* __restrict__ w1t, u16* __restrict__ w2t, float* __restrict__ zbuf)
{
    const int XV = NVOX * 96 / 4;     // 4,800,000 vec4 cast jobs
    const int WC = 62208;             // W chunk jobs per conv (27*36*64)
    int t = blockIdx.x * 256 + threadIdx.x;
    if (blockIdx.x == 0 && threadIdx.x < 64) zbuf[threadIdx.x] = 0.f;
    if (t < XV) {
        float4 v = *(const float4*)(x + (size_t)t * 4);
        ushort4 o;
        o.x = f2bf(v.x); o.y = f2bf(v.y); o.z = f2bf(v.z); o.w = f2bf(v.w);
        *(ushort4*)(xb + (size_t)t * 4) = o;
    } else if (t < XV + WC) {
        int j = t - XV;
        int lane = j & 63, rest = j >> 6;
        int nco = rest % 12, rest2 = rest / 12;
        int ks = rest2 % 3, off = rest2 / 3;
        int co = nco * 16 + (lane & 15);
        int kb = ks * 32 + (lane >> 4) * 8;
        const float* src = W1 + (size_t)off * 18432 + (size_t)kb * 192 + co;
        ushort8v ov;
#pragma unroll
        for (int jj = 0; jj < 8; ++jj) ov[jj] = f2bf(src[(size_t)jj * 192]);
        *(ushort8v*)(w1t + (size_t)j * 8) = ov;
    } else if (t < XV + 2 * WC) {
        int j = t - XV - WC;
        int lane = j & 63, rest = j >> 6;
        int nco = rest % 6, rest2 = rest / 6;
        int kk = rest2 % 6, off = rest2 / 6;
        int co = nco * 16 + (lane & 15);
        int kb = kk * 32 + (lane >> 4) * 8;
        const float* src = W2 + (size_t)off * 18432 + (size_t)kb * 96 + co;
        ushort8v ov;
#pragma unroll
        for (int jj = 0; jj < 8; ++jj) ov[jj] = f2bf(src[(size_t)jj * 96]);
        *(ushort8v*)(w2t + (size_t)j * 8) = ov;
    }
}

// ---------------------------------------------------------------------------
// lsrc precompute: lsrcG[off][row] = mask>0 ? idx : -1  (rows padded to NVP)
// ---------------------------------------------------------------------------
__global__ __launch_bounds__(256) void lsrc_kernel(
    const int* __restrict__ idxp, const int* __restrict__ mskp,
    int* __restrict__ lsrcG)
{
    int r = blockIdx.x * 256 + threadIdx.x;
    int o = blockIdx.y;
    if (r < NVP) {
        int v = -1;
        if (r < NVOX) {
            if (mskp[(size_t)o * NVOX + r] > 0) v = idxp[(size_t)o * NVOX + r];
        }
        lsrcG[(size_t)o * NVP + r] = v;
    }
}

// ---------------------------------------------------------------------------
// conv: explicit-GEMM sparse conv, bf16 MFMA, f32 accum.
//   Fully pinned pipeline (all loop vmem/LDS ops are volatile asm):
//   per iter: [W(s) x9 asm] vmcnt(9) [gather(s+2) x3 gload_lds + sv x1]
//   vmcnt(4) [MFMA w/ asm ds_read pipelined on lgkmcnt(FM)] s_barrier.
//   vmcnt never 0 in loop -> gathers stay in flight ~2 steps.
//   LDS: 3 x [12 planes][128 rows x 16B] (R5/R7 geometry, HW-proven
//   conflict-free).  Epilogue: fused BN partials + bf16 store.
// ---------------------------------------------------------------------------
template<int COUT, int WN, int HFDIV>
__global__ __launch_bounds__(512, 4) void conv_mfma(
    const u16* __restrict__ xb, const int* __restrict__ lsrcG,
    const u16* __restrict__ Wt, const float* __restrict__ zbuf,
    u16* __restrict__ hout, float* __restrict__ part)
{
    constexpr int CIN  = 96 * HFDIV;
    constexpr int WM   = 8 / WN;
    constexpr int FM   = 128 / (WM * 16);   // 4 (conv1) / 2 (conv2)
    constexpr int FN   = COUT / (WN * 16);  // 3 both
    constexpr int NCO  = COUT / 16;
    constexpr int SG   = NOFF * HFDIV;      // 27 / 54
    constexpr int BUFU = 12288;             // u16 per A buffer (24 KB)
    constexpr int WSTP = 3 * NCO * 512;     // W u16 stride per step

    __shared__ u16 ldsA[3 * BUFU];          // 73728 B -> 2 blocks/CU

    const int tid  = threadIdx.x;
    const int row0 = blockIdx.x * 128;
    const int lane = tid & 63;
    const int wid  = tid >> 6;
    const int wm   = wid / WN;
    const int wn   = wid % WN;
    const int lr   = lane & 15;
    const int lk   = lane >> 4;

    const int rStage = tid & 127;           // row this thread stages
    const int c0 = tid >> 7;                // base chunk (c0, c0+4, c0+8)
    const int ldsWaveBase = (tid & ~63) * 8;

    int rdBase[FM];
#pragma unroll
    for (int m = 0; m < FM; ++m) {
        int r = wm * (FM * 16) + m * 16 + lr;
        rdBase[m] = r * 8 + lk * 1024;
    }
    const u16* wtw = Wt + (size_t)(wn * FN) * 512 + (size_t)lane * 8;
    const int* lsp = lsrcG + row0 + rStage;

    f32x4 acc[FM][FN];
#pragma unroll
    for (int m = 0; m < FM; ++m)
#pragma unroll
        for (int n = 0; n < FN; ++n)
            acc[m][n] = (f32x4){0.f, 0.f, 0.f, 0.f};

    auto gatherTo = [&](int sv, int hf, int bsel) {
        const u16* g = (sv >= 0)
            ? (xb + (size_t)sv * CIN + hf * 96 + c0 * 8)
            : ((const u16*)zbuf + c0 * 8);
#pragma unroll
        for (int it = 0; it < 3; ++it)
            GLOAD_LDS16(g + it * 32,
                        ldsA + bsel * BUFU + it * 4096 + ldsWaveBase);
    };
    auto svAddr = [&](int s) -> const int* {
        int idx2 = (s < SG) ? s : (SG - 1);
        int offIdx = (HFDIV == 1) ? idx2 : (idx2 >> 1);
        return lsp + (size_t)offIdx * NVP;
    };

    uint4 wregU[3 * FN];
    auto loadW = [&](const u16* wb) {
#pragma unroll
        for (int ks = 0; ks < 3; ++ks)
#pragma unroll
            for (int n = 0; n < FN; ++n)
                wregU[ks * FN + n] = gld128(wb + (ks * NCO + n) * 512);
    };
    auto mfmaPhase = [&](int cur) {
        const u16* abuf = ldsA + cur * BUFU;
        uint4 a[FM], b[FM];
#pragma unroll
        for (int m = 0; m < FM; ++m) a[m] = dsr128(abuf + rdBase[m]);
#pragma unroll
        for (int m = 0; m < FM; ++m) b[m] = dsr128(abuf + 4096 + rdBase[m]);
        if constexpr (FM == 4) S_WAIT_LG(4); else S_WAIT_LG(2);
        SBAR0();
#pragma unroll
        for (int m = 0; m < FM; ++m)
#pragma unroll
            for (int n = 0; n < FN; ++n)
                acc[m][n] = __builtin_amdgcn_mfma_f32_16x16x32_bf16(
                    as_s8(a[m]), as_s8(wregU[n]), acc[m][n], 0, 0, 0);
#pragma unroll
        for (int m = 0; m < FM; ++m) a[m] = dsr128(abuf + 8192 + rdBase[m]);
        if constexpr (FM == 4) S_WAIT_LG(4); else S_WAIT_LG(2);
        SBAR0();
#pragma unroll
        for (int m = 0; m < FM; ++m)
#pragma unroll
            for (int n = 0; n < FN; ++n)
                acc[m][n] = __builtin_amdgcn_mfma_f32_16x16x32_bf16(
                    as_s8(b[m]), as_s8(wregU[FN + n]), acc[m][n], 0, 0, 0);
        S_WAIT_LG(0);
        SBAR0();
#pragma unroll
        for (int m = 0; m < FM; ++m)
#pragma unroll
            for (int n = 0; n < FN; ++n)
                acc[m][n] = __builtin_amdgcn_mfma_f32_16x16x32_bf16(
                    as_s8(a[m]), as_s8(wregU[2 * FN + n]), acc[m][n], 0, 0, 0);
    };

    // ---- prologue ----
    int sv0 = gld32(svAddr(0));
    int sv1 = gld32(svAddr(1));
    S_WAIT_VM(0); SBAR0();
    gatherTo(sv0, 0, 0);
    gatherTo(sv1, (HFDIV == 1) ? 0 : 1, 1);
    int svPend = gld32(svAddr(2));
    S_WAIT_VM(4); SBAR0();            // g(0) done; [g(1):3, sv(2):1] in flight
    __builtin_amdgcn_s_barrier();
    SBAR0();

    const u16* wb = wtw;
    int cur = 0, nxt2 = 2;
    // ---- steady loop: s = 0 .. SG-3 ----
#pragma unroll 1
    for (int s = 0; s < SG - 2; ++s) {
        loadW(wb);  wb += WSTP;                 // 9 asm loads
        SBAR0();
        S_WAIT_VM(9); SBAR0();                  // g(s+1), sv(s+2) retired
        int sv = svPend;
        gatherTo(sv, (HFDIV == 1) ? 0 : ((s + 2) & 1), nxt2);   // 3 gload_lds
        svPend = gld32(svAddr(s + 3));          // 1 asm load
        SBAR0();
        S_WAIT_VM(4); SBAR0();                  // W(s) retired; g(s+2) flying
        mfmaPhase(cur);
        SBAR0();
        __builtin_amdgcn_s_barrier();           // raw: no vmem drain
        SBAR0();
        cur  = (cur == 2)  ? 0 : cur + 1;
        nxt2 = (nxt2 == 2) ? 0 : nxt2 + 1;
    }
    // ---- peeled s = SG-2 ----
    loadW(wb);  wb += WSTP;
    SBAR0();
    S_WAIT_VM(0); SBAR0();                      // everything retired
    mfmaPhase(cur);
    SBAR0();
    __builtin_amdgcn_s_barrier();
    SBAR0();
    cur = (cur == 2) ? 0 : cur + 1;
    // ---- peeled s = SG-1 ----
    loadW(wb);
    SBAR0();
    S_WAIT_VM(0); SBAR0();
    mfmaPhase(cur);

    // ---- fused BN statsA: per-block partial sum/sumsq per channel ----
    __syncthreads();
    float* smf = (float*)ldsA;             // overlay [WM][COUT][2]
#pragma unroll
    for (int n = 0; n < FN; ++n) {
        float s1 = 0.f, s2 = 0.f;
#pragma unroll
        for (int m = 0; m < FM; ++m)
#pragma unroll
            for (int q = 0; q < 4; ++q) {
                float v = acc[m][n][q];
                s1 += v; s2 += v * v;
            }
        s1 += __shfl_xor(s1, 16); s1 += __shfl_xor(s1, 32);
        s2 += __shfl_xor(s2, 16); s2 += __shfl_xor(s2, 32);
        if (lane < 16) {
            int col = wn * (FN * 16) + n * 16 + lr;
            smf[(wm * COUT + col) * 2 + 0] = s1;
            smf[(wm * COUT + col) * 2 + 1] = s2;
        }
    }
    __syncthreads();
    if (tid < 2 * COUT) {
        int z = tid / COUT, cc = tid % COUT;
        float v = 0.f;
#pragma unroll
        for (int w = 0; w < WM; ++w) v += smf[(w * COUT + cc) * 2 + z];
        part[(size_t)blockIdx.x * (2 * COUT) + z * COUT + cc] = v;
    }

    // ---- store h (bf16): D layout col=lane&15, row=(lane>>4)*4+q ----
#pragma unroll
    for (int m = 0; m < FM; ++m) {
#pragma unroll
        for (int q = 0; q < 4; ++q) {
            int row = row0 + wm * (FM * 16) + m * 16 + lk * 4 + q;
            if (row < NVOX) {
#pragma unroll
                for (int n = 0; n < FN; ++n) {
                    int col = wn * (FN * 16) + n * 16 + lr;
                    hout[(size_t)row * COUT + col] = f2bf(acc[m][n][q]);
                }
            }
        }
    }
}

// ---------------------------------------------------------------------------
// BN stats reduce: sum partials over NBLK blocks, emit scale/shift
// ---------------------------------------------------------------------------
template<int COUT>
__global__ __launch_bounds__(256) void bn_statsB(
    const float* __restrict__ part, const float* __restrict__ g,
    const float* __restrict__ bv, float* __restrict__ ss)
{
    const int c = blockIdx.x;
    const int t = threadIdx.x;
    float s1 = 0.f, s2 = 0.f;
    for (int b = t; b < NBLK; b += 256) {
        s1 += part[(size_t)b * 2 * COUT + c];
        s2 += part[(size_t)b * 2 * COUT + COUT + c];
    }
#pragma unroll
    for (int d = 1; d < 64; d <<= 1) {
        s1 += __shfl_xor(s1, d);
        s2 += __shfl_xor(s2, d);
    }
    __shared__ float rs[8];
    int w = t >> 6;
    if ((t & 63) == 0) { rs[w] = s1; rs[4 + w] = s2; }
    __syncthreads();
    if (t == 0) {
        s1 = rs[0] + rs[1] + rs[2] + rs[3];
        s2 = rs[4] + rs[5] + rs[6] + rs[7];
        float mu  = s1 * (1.0f / NVOX);
        float var = s2 * (1.0f / NVOX) - mu * mu;
        float sc  = g[c] * rsqrtf(var + 1e-5f);
        ss[c] = sc;
        ss[COUT + c] = bv[c] - mu * sc;
    }
}

// ---------------------------------------------------------------------------
// apply BN + ReLU in place (bf16), vec8
// ---------------------------------------------------------------------------
template<int COUT>
__global__ __launch_bounds__(256) void bn_apply_relu(
    u16* __restrict__ h, const float* __restrict__ ss)
{
    int t = blockIdx.x * 256 + threadIdx.x;   // < NVOX*COUT/8
    int c0 = (t * 8) % COUT;
    ushort8v v = *(ushort8v*)(h + (size_t)t * 8);
#pragma unroll
    for (int j = 0; j < 8; ++j) {
        float f = bf2f(v[j]);
        f = fmaxf(f * ss[c0 + j] + ss[COUT + c0 + j], 0.f);
        v[j] = f2bf(f);
    }
    *(ushort8v*)(h + (size_t)t * 8) = v;
}

// ---------------------------------------------------------------------------
// final: out = relu(scale2*h2 + shift2 + x), f32 out, vec8
// ---------------------------------------------------------------------------
__global__ __launch_bounds__(256) void final_kernel(
    const u16* __restrict__ h2, const float* __restrict__ x,
    const float* __restrict__ ss, float* __restrict__ out)
{
    int t = blockIdx.x * 256 + threadIdx.x;   // < NVOX*96/8
    int c0 = (t * 8) % 96;
    ushort8v v = *(const ushort8v*)(h2 + (size_t)t * 8);
    float4 x0 = *(const float4*)(x + (size_t)t * 8);
    float4 x1 = *(const float4*)(x + (size_t)t * 8 + 4);
    float xs[8] = {x0.x, x0.y, x0.z, x0.w, x1.x, x1.y, x1.z, x1.w};
    float o[8];
#pragma unroll
    for (int j = 0; j < 8; ++j) {
        float f = bf2f(v[j]) * ss[c0 + j] + ss[96 + c0 + j] + xs[j];
        o[j] = fmaxf(f, 0.f);
    }
    *(float4*)(out + (size_t)t * 8)     = (float4){o[0], o[1], o[2], o[3]};
    *(float4*)(out + (size_t)t * 8 + 4) = (float4){o[4], o[5], o[6], o[7]};
}

// ---------------------------------------------------------------------------
extern "C" void kernel_launch(void* const* d_in, const int* in_sizes, int n_in,
                              void* d_out, int out_size, void* d_ws, size_t ws_size,
                              hipStream_t stream)
{
    const float* x    = (const float*)d_in[0];
    const int*   idx  = (const int*)d_in[1];
    const int*   mask = (const int*)d_in[2];
    const float* W1   = (const float*)d_in[3];
    const float* g1   = (const float*)d_in[4];
    const float* b1   = (const float*)d_in[5];
    const float* W2   = (const float*)d_in[6];
    const float* g2   = (const float*)d_in[7];
    const float* b2   = (const float*)d_in[8];

    unsigned char* ws = (unsigned char*)d_ws;
    u16*  xb    = (u16*)ws;                          // 38,400,000 B
    u16*  w1t   = (u16*)(ws + 38400000);             //    995,328 B
    u16*  w2t   = (u16*)(ws + 39395328);             //    995,328 B
    u16*  h2    = (u16*)(ws + 40390656);             // 38,400,000 B
    float* part = (float*)(ws + 78790656);           //  2,400,768 B
    float* ss1  = (float*)(ws + 81191424);           //      1,536 B
    float* ss2  = (float*)(ws + 81192960);           //        768 B
    float* zbuf = (float*)(ws + 81193728);           //        256 B
    int*  lsrcG = (int*)(ws + 81193984);             // 21,606,912 B

    u16* h = (u16*)d_out;         // reuse d_out (76.8MB) as [N][192] bf16

    prep_kernel<<<19236, 256, 0, stream>>>(x, W1, W2, xb, w1t, w2t, zbuf);
    lsrc_kernel<<<dim3(782, 27), 256, 0, stream>>>(idx, mask, lsrcG);

    // conv1: COUT=192, 2m x 4n waves (FM=4, FN=3), K=96 per offset
    conv_mfma<192, 4, 1><<<NBLK, 512, 0, stream>>>(xb, lsrcG, w1t, zbuf, h, part);
    bn_statsB<192><<<192, 256, 0, stream>>>(part, g1, b1, ss1);
    bn_apply_relu<192><<<18750, 256, 0, stream>>>(h, ss1);

    // conv2: COUT=96, 4m x 2n waves (FM=2, FN=3), K=192 in two 96-phases
    conv_mfma<96, 2, 2><<<NBLK, 512, 0, stream>>>(h, lsrcG, w2t, zbuf, h2, part);
    bn_statsB<96><<<96, 256, 0, stream>>>(part, g2, b2, ss2);
    final_kernel<<<9375, 256, 0, stream>>>(h2, x, ss2, (float*)d_out);
}

// Round 10
// 703.537 us; speedup vs baseline: 2.3163x; 1.0312x over previous
//
#include <hip/hip_runtime.h>
#include <hip/hip_bf16.h>

typedef unsigned short u16;
typedef __attribute__((ext_vector_type(8))) short short8;
typedef __attribute__((ext_vector_type(4))) float f32x4;
typedef __attribute__((ext_vector_type(8))) unsigned short ushort8v;

#define NVOX 200000
#define NVP  200064
#define NOFF 27
#define NBLK 1563

__device__ __forceinline__ u16 f2bf(float f) {
    __hip_bfloat16 h = __float2bfloat16(f);
    return *reinterpret_cast<u16*>(&h);
}
__device__ __forceinline__ float bf2f(u16 u) {
    union { unsigned int i; float f; } v;
    v.i = ((unsigned int)u) << 16;
    return v.f;
}

#define GLOAD_LDS16(g, l)                                                     \
    __builtin_amdgcn_global_load_lds(                                         \
        (const __attribute__((address_space(1))) unsigned int*)(g),           \
        (__attribute__((address_space(3))) unsigned int*)(l), 16, 0, 0)

// compiler-proof loads (volatile asm: cannot be sunk/reordered/auto-waited)
__device__ __forceinline__ uint4 gld128(const u16* p) {
    uint4 r;
    asm volatile("global_load_dwordx4 %0, %1, off" : "=v"(r) : "v"(p) : "memory");
    return r;
}
__device__ __forceinline__ int gld32(const int* p) {
    int r;
    asm volatile("global_load_dword %0, %1, off" : "=v"(r) : "v"(p) : "memory");
    return r;
}
__device__ __forceinline__ uint4 dsr128(const u16* p) {
    uint4 r;
    asm volatile("ds_read_b128 %0, %1"
                 : "=v"(r)
                 : "v"((const __attribute__((address_space(3))) uint4*)p));
    return r;
}
__device__ __forceinline__ short8 as_s8(uint4 v) {
    union { uint4 u; short8 s; } c; c.u = v; return c.s;
}
#define S_WAIT_VM(n) asm volatile("s_waitcnt vmcnt(" #n ")" ::: "memory")
#define S_WAIT_LG(n) asm volatile("s_waitcnt lgkmcnt(" #n ")" ::: "memory")
#define SBAR0()      __builtin_amdgcn_sched_barrier(0)

// ---------------------------------------------------------------------------
// prep: cast x -> bf16; repack W1/W2 fragment-major; zero page.
// ---------------------------------------------------------------------------
__global__ __launch_bounds__(256) void prep_kernel(
    const float* __restrict__ x, const float* __restrict__ W1,
    const float* __restrict__ W2, u16* __restrict__ xb,
    u16* __restrict__ w1t, u16* __restrict__ w2t, float* __restrict__ zbuf)
{
    const int XV = NVOX * 96 / 4;     // 4,800,000 vec4 cast jobs
    const int WC = 62208;             // W chunk jobs per conv (27*36*64)
    int t = blockIdx.x * 256 + threadIdx.x;
    if (blockIdx.x == 0 && threadIdx.x < 64) zbuf[threadIdx.x] = 0.f;
    if (t < XV) {
        float4 v = *(const float4*)(x + (size_t)t * 4);
        ushort4 o;
        o.x = f2bf(v.x); o.y = f2bf(v.y); o.z = f2bf(v.z); o.w = f2bf(v.w);
        *(ushort4*)(xb + (size_t)t * 4) = o;
    } else if (t < XV + WC) {
        int j = t - XV;
        int lane = j & 63, rest = j >> 6;
        int nco = rest % 12, rest2 = rest / 12;
        int ks = rest2 % 3, off = rest2 / 3;
        int co = nco * 16 + (lane & 15);
        int kb = ks * 32 + (lane >> 4) * 8;
        const float* src = W1 + (size_t)off * 18432 + (size_t)kb * 192 + co;
        ushort8v ov;
#pragma unroll
        for (int jj = 0; jj < 8; ++jj) ov[jj] = f2bf(src[(size_t)jj * 192]);
        *(ushort8v*)(w1t + (size_t)j * 8) = ov;
    } else if (t < XV + 2 * WC) {
        int j = t - XV - WC;
        int lane = j & 63, rest = j >> 6;
        int nco = rest % 6, rest2 = rest / 6;
        int kk = rest2 % 6, off = rest2 / 6;
        int co = nco * 16 + (lane & 15);
        int kb = kk * 32 + (lane >> 4) * 8;
        const float* src = W2 + (size_t)off * 18432 + (size_t)kb * 96 + co;
        ushort8v ov;
#pragma unroll
        for (int jj = 0; jj < 8; ++jj) ov[jj] = f2bf(src[(size_t)jj * 96]);
        *(ushort8v*)(w2t + (size_t)j * 8) = ov;
    }
}

// ---------------------------------------------------------------------------
// lsrc precompute: lsrcG[off][row] = mask>0 ? idx : -1  (rows padded to NVP)
// ---------------------------------------------------------------------------
__global__ __launch_bounds__(256) void lsrc_kernel(
    const int* __restrict__ idxp, const int* __restrict__ mskp,
    int* __restrict__ lsrcG)
{
    int r = blockIdx.x * 256 + threadIdx.x;
    int o = blockIdx.y;
    if (r < NVP) {
        int v = -1;
        if (r < NVOX) {
            if (mskp[(size_t)o * NVOX + r] > 0) v = idxp[(size_t)o * NVOX + r];
        }
        lsrcG[(size_t)o * NVP + r] = v;
    }
}

// ---------------------------------------------------------------------------
// conv: explicit-GEMM sparse conv, bf16 MFMA, f32 accum.
//   Gather lane-map is TA-merge-friendly: wave w, lane l stages row
//   w*16+(l&15), chunk 4*it+(l>>4) -> the 4 lanes of one 64B line are
//   adjacent in-wave -> 16 line-transactions per gather instr (4x fewer).
//   LDS read stays canonical conflict-free (1024 contiguous B per wave).
//   Pinned pipeline (volatile asm), counted vmcnt, never 0 in loop.
//   Epilogue: fused BN partials + bf16 store.
// ---------------------------------------------------------------------------
template<int COUT, int WN, int HFDIV>
__global__ __launch_bounds__(512, 4) void conv_mfma(
    const u16* __restrict__ xb, const int* __restrict__ lsrcG,
    const u16* __restrict__ Wt, const float* __restrict__ zbuf,
    u16* __restrict__ hout, float* __restrict__ part)
{
    constexpr int CIN  = 96 * HFDIV;
    constexpr int WM   = 8 / WN;
    constexpr int FM   = 128 / (WM * 16);   // 4 (conv1) / 2 (conv2)
    constexpr int FN   = COUT / (WN * 16);  // 3 both
    constexpr int NCO  = COUT / 16;
    constexpr int SG   = NOFF * HFDIV;      // 27 / 54
    constexpr int BUFU = 12288;             // u16 per A buffer (24 KB)
    constexpr int WSTP = 3 * NCO * 512;     // W u16 stride per step

    __shared__ u16 ldsA[3 * BUFU];          // 73728 B -> 2 blocks/CU

    const int tid  = threadIdx.x;
    const int row0 = blockIdx.x * 128;
    const int lane = tid & 63;
    const int wid  = tid >> 6;
    const int wm   = wid / WN;
    const int wn   = wid % WN;
    const int lr   = lane & 15;
    const int lk   = lane >> 4;

    // staging map: this thread stages row wid*16+(lane&15), chunks
    // 4*it + (lane>>4); 4 adjacent lanes cover one 64B line (TA merge).
    const int rStage = wid * 16 + (lane & 15);
    const int cBase  = (lane >> 4) * 8;       // u16 offset of chunk in row
    const int ldsWaveBase = wid * 512;        // u16; HW adds lane*16B

    // read map: af[m](ks) at u16 offset ks*4096 + (wm*FM+m)*512 + lr*8 + lk*128
    int rdBase[FM];
#pragma unroll
    for (int m = 0; m < FM; ++m)
        rdBase[m] = (wm * FM + m) * 512 + lr * 8 + lk * 128;
    const u16* wtw = Wt + (size_t)(wn * FN) * 512 + (size_t)lane * 8;
    const int* lsp = lsrcG + row0 + rStage;

    f32x4 acc[FM][FN];
#pragma unroll
    for (int m = 0; m < FM; ++m)
#pragma unroll
        for (int n = 0; n < FN; ++n)
            acc[m][n] = (f32x4){0.f, 0.f, 0.f, 0.f};

    auto gatherTo = [&](int sv, int hf, int bsel) {
        const u16* g = (sv >= 0)
            ? (xb + (size_t)sv * CIN + hf * 96 + cBase)
            : ((const u16*)zbuf + cBase);
#pragma unroll
        for (int it = 0; it < 3; ++it)
            GLOAD_LDS16(g + it * 32,
                        ldsA + bsel * BUFU + it * 4096 + ldsWaveBase);
    };
    auto svAddr = [&](int s) -> const int* {
        int idx2 = (s < SG) ? s : (SG - 1);
        int offIdx = (HFDIV == 1) ? idx2 : (idx2 >> 1);
        return lsp + (size_t)offIdx * NVP;
    };

    uint4 wregU[3 * FN];
    auto loadW = [&](const u16* wb) {
#pragma unroll
        for (int ks = 0; ks < 3; ++ks)
#pragma unroll
            for (int n = 0; n < FN; ++n)
                wregU[ks * FN + n] = gld128(wb + (ks * NCO + n) * 512);
    };
    auto mfmaPhase = [&](int cur) {
        const u16* abuf = ldsA + cur * BUFU;
        uint4 a[FM], b[FM];
#pragma unroll
        for (int m = 0; m < FM; ++m) a[m] = dsr128(abuf + rdBase[m]);
#pragma unroll
        for (int m = 0; m < FM; ++m) b[m] = dsr128(abuf + 4096 + rdBase[m]);
        if constexpr (FM == 4) S_WAIT_LG(4); else S_WAIT_LG(2);
        SBAR0();
#pragma unroll
        for (int m = 0; m < FM; ++m)
#pragma unroll
            for (int n = 0; n < FN; ++n)
                acc[m][n] = __builtin_amdgcn_mfma_f32_16x16x32_bf16(
                    as_s8(a[m]), as_s8(wregU[n]), acc[m][n], 0, 0, 0);
#pragma unroll
        for (int m = 0; m < FM; ++m) a[m] = dsr128(abuf + 8192 + rdBase[m]);
        if constexpr (FM == 4) S_WAIT_LG(4); else S_WAIT_LG(2);
        SBAR0();
#pragma unroll
        for (int m = 0; m < FM; ++m)
#pragma unroll
            for (int n = 0; n < FN; ++n)
                acc[m][n] = __builtin_amdgcn_mfma_f32_16x16x32_bf16(
                    as_s8(b[m]), as_s8(wregU[FN + n]), acc[m][n], 0, 0, 0);
        S_WAIT_LG(0);
        SBAR0();
#pragma unroll
        for (int m = 0; m < FM; ++m)
#pragma unroll
            for (int n = 0; n < FN; ++n)
                acc[m][n] = __builtin_amdgcn_mfma_f32_16x16x32_bf16(
                    as_s8(a[m]), as_s8(wregU[2 * FN + n]), acc[m][n], 0, 0, 0);
    };

    // ---- prologue ----
    int sv0 = gld32(svAddr(0));
    int sv1 = gld32(svAddr(1));
    S_WAIT_VM(0); SBAR0();
    gatherTo(sv0, 0, 0);
    gatherTo(sv1, (HFDIV == 1) ? 0 : 1, 1);
    int svPend = gld32(svAddr(2));
    S_WAIT_VM(4); SBAR0();            // g(0) done; [g(1):3, sv(2):1] in flight
    __builtin_amdgcn_s_barrier();
    SBAR0();

    const u16* wb = wtw;
    int cur = 0, nxt2 = 2;
    // ---- steady loop: s = 0 .. SG-3 ----
#pragma unroll 1
    for (int s = 0; s < SG - 2; ++s) {
        loadW(wb);  wb += WSTP;                 // 9 asm loads
        SBAR0();
        S_WAIT_VM(9); SBAR0();                  // g(s+1), sv(s+2) retired
        int sv = svPend;
        gatherTo(sv, (HFDIV == 1) ? 0 : ((s + 2) & 1), nxt2);   // 3 gload_lds
        svPend = gld32(svAddr(s + 3));          // 1 asm load
        SBAR0();
        S_WAIT_VM(4); SBAR0();                  // W(s) retired; g(s+2) flying
        mfmaPhase(cur);
        SBAR0();
        __builtin_amdgcn_s_barrier();           // raw: no vmem drain
        SBAR0();
        cur  = (cur == 2)  ? 0 : cur + 1;
        nxt2 = (nxt2 == 2) ? 0 : nxt2 + 1;
    }
    // ---- peeled s = SG-2 ----
    loadW(wb);  wb += WSTP;
    SBAR0();
    S_WAIT_VM(0); SBAR0();                      // everything retired
    mfmaPhase(cur);
    SBAR0();
    __builtin_amdgcn_s_barrier();
    SBAR0();
    cur = (cur == 2) ? 0 : cur + 1;
    // ---- peeled s = SG-1 ----
    loadW(wb);
    SBAR0();
    S_WAIT_VM(0); SBAR0();
    mfmaPhase(cur);

    // ---- fused BN statsA: per-block partial sum/sumsq per channel ----
    __syncthreads();
    float* smf = (float*)ldsA;             // overlay [WM][COUT][2]
#pragma unroll
    for (int n = 0; n < FN; ++n) {
        float s1 = 0.f, s2 = 0.f;
#pragma unroll
        for (int m = 0; m < FM; ++m)
#pragma unroll
            for (int q = 0; q < 4; ++q) {
                float v = acc[m][n][q];
                s1 += v; s2 += v * v;
            }
        s1 += __shfl_xor(s1, 16); s1 += __shfl_xor(s1, 32);
        s2 += __shfl_xor(s2, 16); s2 += __shfl_xor(s2, 32);
        if (lane < 16) {
            int col = wn * (FN * 16) + n * 16 + lr;
            smf[(wm * COUT + col) * 2 + 0] = s1;
            smf[(wm * COUT + col) * 2 + 1] = s2;
        }
    }
    __syncthreads();
    if (tid < 2 * COUT) {
        int z = tid / COUT, cc = tid % COUT;
        float v = 0.f;
#pragma unroll
        for (int w = 0; w < WM; ++w) v += smf[(w * COUT + cc) * 2 + z];
        part[(size_t)blockIdx.x * (2 * COUT) + z * COUT + cc] = v;
    }

    // ---- store h (bf16): D layout col=lane&15, row=(lane>>4)*4+q ----
#pragma unroll
    for (int m = 0; m < FM; ++m) {
#pragma unroll
        for (int q = 0; q < 4; ++q) {
            int row = row0 + wm * (FM * 16) + m * 16 + lk * 4 + q;
            if (row < NVOX) {
#pragma unroll
                for (int n = 0; n < FN; ++n) {
                    int col = wn * (FN * 16) + n * 16 + lr;
                    hout[(size_t)row * COUT + col] = f2bf(acc[m][n][q]);
                }
            }
        }
    }
}

// ---------------------------------------------------------------------------
// BN stats reduce: sum partials over NBLK blocks, emit scale/shift
// ---------------------------------------------------------------------------
template<int COUT>
__global__ __launch_bounds__(256) void bn_statsB(
    const float* __restrict__ part, const float* __restrict__ g,
    const float* __restrict__ bv, float* __restrict__ ss)
{
    const int c = blockIdx.x;
    const int t = threadIdx.x;
    float s1 = 0.f, s2 = 0.f;
    for (int b = t; b < NBLK; b += 256) {
        s1 += part[(size_t)b * 2 * COUT + c];
        s2 += part[(size_t)b * 2 * COUT + COUT + c];
    }
#pragma unroll
    for (int d = 1; d < 64; d <<= 1) {
        s1 += __shfl_xor(s1, d);
        s2 += __shfl_xor(s2, d);
    }
    __shared__ float rs[8];
    int w = t >> 6;
    if ((t & 63) == 0) { rs[w] = s1; rs[4 + w] = s2; }
    __syncthreads();
    if (t == 0) {
        s1 = rs[0] + rs[1] + rs[2] + rs[3];
        s2 = rs[4] + rs[5] + rs[6] + rs[7];
        float mu  = s1 * (1.0f / NVOX);
        float var = s2 * (1.0f / NVOX) - mu * mu;
        float sc  = g[c] * rsqrtf(var + 1e-5f);
        ss[c] = sc;
        ss[COUT + c] = bv[c] - mu * sc;
    }
}

// ---------------------------------------------------------------------------
// apply BN + ReLU in place (bf16), vec8
// ---------------------------------------------------------------------------
template<int COUT>
__global__ __launch_bounds__(256) void bn_apply_relu(
    u16* __restrict__ h, const float* __restrict__ ss)
{
    int t = blockIdx.x * 256 + threadIdx.x;   // < NVOX*COUT/8
    int c0 = (t * 8) % COUT;
    ushort8v v = *(ushort8v*)(h + (size_t)t * 8);
#pragma unroll
    for (int j = 0; j < 8; ++j) {
        float f = bf2f(v[j]);
        f = fmaxf(f * ss[c0 + j] + ss[COUT + c0 + j], 0.f);
        v[j] = f2bf(f);
    }
    *(ushort8v*)(h + (size_t)t * 8) = v;
}

// ---------------------------------------------------------------------------
// final: out = relu(scale2*h2 + shift2 + x), f32 out, vec8
// ---------------------------------------------------------------------------
__global__ __launch_bounds__(256) void final_kernel(
    const u16* __restrict__ h2, const float* __restrict__ x,
    const float* __restrict__ ss, float* __restrict__ out)
{
    int t = blockIdx.x * 256 + threadIdx.x;   // < NVOX*96/8
    int c0 = (t * 8) % 96;
    ushort8v v = *(const ushort8v*)(h2 + (size_t)t * 8);
    float4 x0 = *(const float4*)(x + (size_t)t * 8);
    float4 x1 = *(const float4*)(x + (size_t)t * 8 + 4);
    float xs[8] = {x0.x, x0.y, x0.z, x0.w, x1.x, x1.y, x1.z, x1.w};
    float o[8];
#pragma unroll
    for (int j = 0; j < 8; ++j) {
        float f = bf2f(v[j]) * ss[c0 + j] + ss[96 + c0 + j] + xs[j];
        o[j] = fmaxf(f, 0.f);
    }
    *(float4*)(out + (size_t)t * 8)     = (float4){o[0], o[1], o[2], o[3]};
    *(float4*)(out + (size_t)t * 8 + 4) = (float4){o[4], o[5], o[6], o[7]};
}

// ---------------------------------------------------------------------------
extern "C" void kernel_launch(void* const* d_in, const int* in_sizes, int n_in,
                              void* d_out, int out_size, void* d_ws, size_t ws_size,
                              hipStream_t stream)
{
    const float* x    = (const float*)d_in[0];
    const int*   idx  = (const int*)d_in[1];
    const int*   mask = (const int*)d_in[2];
    const float* W1   = (const float*)d_in[3];
    const float* g1   = (const float*)d_in[4];
    const float* b1   = (const float*)d_in[5];
    const float* W2   = (const float*)d_in[6];
    const float* g2   = (const float*)d_in[7];
    const float* b2   = (const float*)d_in[8];

    unsigned char* ws = (unsigned char*)d_ws;
    u16*  xb    = (u16*)ws;                          // 38,400,000 B
    u16*  w1t   = (u16*)(ws + 38400000);             //    995,328 B
    u16*  w2t   = (u16*)(ws + 39395328);             //    995,328 B
    u16*  h2    = (u16*)(ws + 40390656);             // 38,400,000 B
    float* part = (float*)(ws + 78790656);           //  2,400,768 B
    float* ss1  = (float*)(ws + 81191424);           //      1,536 B
    float* ss2  = (float*)(ws + 81192960);           //        768 B
    float* zbuf = (float*)(ws + 81193728);           //        256 B
    int*  lsrcG = (int*)(ws + 81193984);             // 21,606,912 B

    u16* h = (u16*)d_out;         // reuse d_out (76.8MB) as [N][192] bf16

    prep_kernel<<<19236, 256, 0, stream>>>(x, W1, W2, xb, w1t, w2t, zbuf);
    lsrc_kernel<<<dim3(782, 27), 256, 0, stream>>>(idx, mask, lsrcG);

    // conv1: COUT=192, 2m x 4n waves (FM=4, FN=3), K=96 per offset
    conv_mfma<192, 4, 1><<<NBLK, 512, 0, stream>>>(xb, lsrcG, w1t, zbuf, h, part);
    bn_statsB<192><<<192, 256, 0, stream>>>(part, g1, b1, ss1);
    bn_apply_relu<192><<<18750, 256, 0, stream>>>(h, ss1);

    // conv2: COUT=96, 4m x 2n waves (FM=2, FN=3), K=192 in two 96-phases
    conv_mfma<96, 2, 2><<<NBLK, 512, 0, stream>>>(h, lsrcG, w2t, zbuf, h2, part);
    bn_statsB<96><<<96, 256, 0, stream>>>(part, g2, b2, ss2);
    final_kernel<<<9375, 256, 0, stream>>>(h2, x, ss2, (float*)d_out);
}

// Round 11
// 683.613 us; speedup vs baseline: 2.3838x; 1.0291x over previous
//
#include <hip/hip_runtime.h>
#include <hip/hip_bf16.h>

typedef unsigned short u16;
typedef __attribute__((ext_vector_type(8))) short short8;
typedef __attribute__((ext_vector_type(4))) float f32x4;
typedef __attribute__((ext_vector_type(8))) unsigned short ushort8v;

#define NVOX 200000
#define NVP  200064
#define NOFF 27
#define NBLK 1563

__device__ __forceinline__ u16 f2bf(float f) {
    __hip_bfloat16 h = __float2bfloat16(f);
    return *reinterpret_cast<u16*>(&h);
}
__device__ __forceinline__ float bf2f(u16 u) {
    union { unsigned int i; float f; } v;
    v.i = ((unsigned int)u) << 16;
    return v.f;
}

#define GLOAD_LDS16(g, l)                                                     \
    __builtin_amdgcn_global_load_lds(                                         \
        (const __attribute__((address_space(1))) unsigned int*)(g),           \
        (__attribute__((address_space(3))) unsigned int*)(l), 16, 0, 0)

// compiler-proof loads (volatile asm: cannot be sunk/reordered/auto-waited)
__device__ __forceinline__ uint4 gld128(const u16* p) {
    uint4 r;
    asm volatile("global_load_dwordx4 %0, %1, off" : "=v"(r) : "v"(p) : "memory");
    return r;
}
__device__ __forceinline__ int gld32(const int* p) {
    int r;
    asm volatile("global_load_dword %0, %1, off" : "=v"(r) : "v"(p) : "memory");
    return r;
}
__device__ __forceinline__ uint4 dsr128(const u16* p) {
    uint4 r;
    asm volatile("ds_read_b128 %0, %1"
                 : "=v"(r)
                 : "v"((const __attribute__((address_space(3))) uint4*)p));
    return r;
}
__device__ __forceinline__ short8 as_s8(uint4 v) {
    union { uint4 u; short8 s; } c; c.u = v; return c.s;
}
#define S_WAIT_VM(n) asm volatile("s_waitcnt vmcnt(" #n ")" ::: "memory")
#define S_WAIT_LG(n) asm volatile("s_waitcnt lgkmcnt(" #n ")" ::: "memory")
#define SBAR0()      __builtin_amdgcn_sched_barrier(0)

// ---------------------------------------------------------------------------
// prep: cast x -> bf16; repack W1/W2 fragment-major; zero page.
// ---------------------------------------------------------------------------
__global__ __launch_bounds__(256) void prep_kernel(
    const float* __restrict__ x, const float* __restrict__ W1,
    const float* __restrict__ W2, u16* __restrict__ xb,
    u16* __restrict__ w1t, u16* __restrict__ w2t, float* __restrict__ zbuf)
{
    const int XV = NVOX * 96 / 4;     // 4,800,000 vec4 cast jobs
    const int WC = 62208;             // W chunk jobs per conv (27*36*64)
    int t = blockIdx.x * 256 + threadIdx.x;
    if (blockIdx.x == 0 && threadIdx.x < 64) zbuf[threadIdx.x] = 0.f;
    if (t < XV) {
        float4 v = *(const float4*)(x + (size_t)t * 4);
        ushort4 o;
        o.x = f2bf(v.x); o.y = f2bf(v.y); o.z = f2bf(v.z); o.w = f2bf(v.w);
        *(ushort4*)(xb + (size_t)t * 4) = o;
    } else if (t < XV + WC) {
        int j = t - XV;
        int lane = j & 63, rest = j >> 6;
        int nco = rest % 12, rest2 = rest / 12;
        int ks = rest2 % 3, off = rest2 / 3;
        int co = nco * 16 + (lane & 15);
        int kb = ks * 32 + (lane >> 4) * 8;
        const float* src = W1 + (size_t)off * 18432 + (size_t)kb * 192 + co;
        ushort8v ov;
#pragma unroll
        for (int jj = 0; jj < 8; ++jj) ov[jj] = f2bf(src[(size_t)jj * 192]);
        *(ushort8v*)(w1t + (size_t)j * 8) = ov;
    } else if (t < XV + 2 * WC) {
        int j = t - XV - WC;
        int lane = j & 63, rest = j >> 6;
        int nco = rest % 6, rest2 = rest / 6;
        int kk = rest2 % 6, off = rest2 / 6;
        int co = nco * 16 + (lane & 15);
        int kb = kk * 32 + (lane >> 4) * 8;
        const float* src = W2 + (size_t)off * 18432 + (size_t)kb * 96 + co;
        ushort8v ov;
#pragma unroll
        for (int jj = 0; jj < 8; ++jj) ov[jj] = f2bf(src[(size_t)jj * 96]);
        *(ushort8v*)(w2t + (size_t)j * 8) = ov;
    }
}

// ---------------------------------------------------------------------------
// lsrc precompute: lsrcG[off][row] = mask>0 ? idx : -1  (rows padded to NVP)
// ---------------------------------------------------------------------------
__global__ __launch_bounds__(256) void lsrc_kernel(
    const int* __restrict__ idxp, const int* __restrict__ mskp,
    int* __restrict__ lsrcG)
{
    int r = blockIdx.x * 256 + threadIdx.x;
    int o = blockIdx.y;
    if (r < NVP) {
        int v = -1;
        if (r < NVOX) {
            if (mskp[(size_t)o * NVOX + r] > 0) v = idxp[(size_t)o * NVOX + r];
        }
        lsrcG[(size_t)o * NVP + r] = v;
    }
}

// ---------------------------------------------------------------------------
// conv: explicit-GEMM sparse conv, bf16 MFMA, f32 accum.
//   Conditional gather: active lanes (sv>=0) issue global_load_lds (EXEC-
//   masked, each active lane writes base+lane*16B); masked lanes write
//   zeros into their own LDS slots via ds_write_b128 -> NO global request
//   for masked rows (halves gather request count vs R10's zbuf reads).
//   Zero-writes drain via the wave's lgkmcnt(0) inside the MFMA phase,
//   two barriers before any consumer reads the buffer.
//   Pinned pipeline (volatile asm), counted vmcnt, never 0 in loop.
//   Epilogue: fused BN partials + bf16 store.
// ---------------------------------------------------------------------------
template<int COUT, int WN, int HFDIV>
__global__ __launch_bounds__(512, 4) void conv_mfma(
    const u16* __restrict__ xb, const int* __restrict__ lsrcG,
    const u16* __restrict__ Wt, const float* __restrict__ zbuf,
    u16* __restrict__ hout, float* __restrict__ part)
{
    constexpr int CIN  = 96 * HFDIV;
    constexpr int WM   = 8 / WN;
    constexpr int FM   = 128 / (WM * 16);   // 4 (conv1) / 2 (conv2)
    constexpr int FN   = COUT / (WN * 16);  // 3 both
    constexpr int NCO  = COUT / 16;
    constexpr int SG   = NOFF * HFDIV;      // 27 / 54
    constexpr int BUFU = 12288;             // u16 per A buffer (24 KB)
    constexpr int WSTP = 3 * NCO * 512;     // W u16 stride per step

    __shared__ u16 ldsA[3 * BUFU];          // 73728 B -> 2 blocks/CU

    const int tid  = threadIdx.x;
    const int row0 = blockIdx.x * 128;
    const int lane = tid & 63;
    const int wid  = tid >> 6;
    const int wm   = wid / WN;
    const int wn   = wid % WN;
    const int lr   = lane & 15;
    const int lk   = lane >> 4;

    // staging map: this thread stages row wid*16+(lane&15), chunks
    // 4*it + (lane>>4); 4 adjacent lanes cover one 64B line (TA merge).
    const int rStage = wid * 16 + (lane & 15);
    const int cBase  = (lane >> 4) * 8;       // u16 offset of chunk in row
    const int ldsWaveBase = wid * 512;        // u16; HW adds lane*16B
    const int ldsLaneSlot = ldsWaveBase + lane * 8;   // this lane's u16 slot

    // read map: af[m](ks) at u16 offset ks*4096 + (wm*FM+m)*512 + lr*8 + lk*128
    int rdBase[FM];
#pragma unroll
    for (int m = 0; m < FM; ++m)
        rdBase[m] = (wm * FM + m) * 512 + lr * 8 + lk * 128;
    const u16* wtw = Wt + (size_t)(wn * FN) * 512 + (size_t)lane * 8;
    const int* lsp = lsrcG + row0 + rStage;

    f32x4 acc[FM][FN];
#pragma unroll
    for (int m = 0; m < FM; ++m)
#pragma unroll
        for (int n = 0; n < FN; ++n)
            acc[m][n] = (f32x4){0.f, 0.f, 0.f, 0.f};

    auto gatherTo = [&](int sv, int hf, int bsel) {
        if (sv >= 0) {
            const u16* g = xb + (size_t)sv * CIN + hf * 96 + cBase;
#pragma unroll
            for (int it = 0; it < 3; ++it)
                GLOAD_LDS16(g + it * 32,
                            ldsA + bsel * BUFU + it * 4096 + ldsWaveBase);
        } else {
            const uint4 z = {0u, 0u, 0u, 0u};
#pragma unroll
            for (int it = 0; it < 3; ++it)
                *(uint4*)(ldsA + bsel * BUFU + it * 4096 + ldsLaneSlot) = z;
        }
    };
    auto svAddr = [&](int s) -> const int* {
        int idx2 = (s < SG) ? s : (SG - 1);
        int offIdx = (HFDIV == 1) ? idx2 : (idx2 >> 1);
        return lsp + (size_t)offIdx * NVP;
    };

    uint4 wregU[3 * FN];
    auto loadW = [&](const u16* wb) {
#pragma unroll
        for (int ks = 0; ks < 3; ++ks)
#pragma unroll
            for (int n = 0; n < FN; ++n)
                wregU[ks * FN + n] = gld128(wb + (ks * NCO + n) * 512);
    };
    auto mfmaPhase = [&](int cur) {
        const u16* abuf = ldsA + cur * BUFU;
        uint4 a[FM], b[FM];
#pragma unroll
        for (int m = 0; m < FM; ++m) a[m] = dsr128(abuf + rdBase[m]);
#pragma unroll
        for (int m = 0; m < FM; ++m) b[m] = dsr128(abuf + 4096 + rdBase[m]);
        if constexpr (FM == 4) S_WAIT_LG(4); else S_WAIT_LG(2);
        SBAR0();
#pragma unroll
        for (int m = 0; m < FM; ++m)
#pragma unroll
            for (int n = 0; n < FN; ++n)
                acc[m][n] = __builtin_amdgcn_mfma_f32_16x16x32_bf16(
                    as_s8(a[m]), as_s8(wregU[n]), acc[m][n], 0, 0, 0);
#pragma unroll
        for (int m = 0; m < FM; ++m) a[m] = dsr128(abuf + 8192 + rdBase[m]);
        if constexpr (FM == 4) S_WAIT_LG(4); else S_WAIT_LG(2);
        SBAR0();
#pragma unroll
        for (int m = 0; m < FM; ++m)
#pragma unroll
            for (int n = 0; n < FN; ++n)
                acc[m][n] = __builtin_amdgcn_mfma_f32_16x16x32_bf16(
                    as_s8(b[m]), as_s8(wregU[FN + n]), acc[m][n], 0, 0, 0);
        S_WAIT_LG(0);
        SBAR0();
#pragma unroll
        for (int m = 0; m < FM; ++m)
#pragma unroll
            for (int n = 0; n < FN; ++n)
                acc[m][n] = __builtin_amdgcn_mfma_f32_16x16x32_bf16(
                    as_s8(a[m]), as_s8(wregU[2 * FN + n]), acc[m][n], 0, 0, 0);
    };

    // ---- prologue ----
    int sv0 = gld32(svAddr(0));
    int sv1 = gld32(svAddr(1));
    S_WAIT_VM(0); SBAR0();
    gatherTo(sv0, 0, 0);
    gatherTo(sv1, (HFDIV == 1) ? 0 : 1, 1);
    int svPend = gld32(svAddr(2));
    S_WAIT_VM(1); SBAR0();            // all gathers done; sv(2) may fly
    S_WAIT_LG(0);                     // zero-writes done
    __builtin_amdgcn_s_barrier();
    SBAR0();

    const u16* wb = wtw;
    int cur = 0, nxt2 = 2;
    // ---- steady loop: s = 0 .. SG-3 ----
#pragma unroll 1
    for (int s = 0; s < SG - 2; ++s) {
        loadW(wb);  wb += WSTP;                 // 9 asm loads
        SBAR0();
        S_WAIT_VM(9); SBAR0();                  // g(s+1), sv(s+2) retired
        int sv = svPend;
        gatherTo(sv, (HFDIV == 1) ? 0 : ((s + 2) & 1), nxt2);
        svPend = gld32(svAddr(s + 3));          // 1 asm load
        SBAR0();
        // W(s) retired; g(s+2) stays in flight (count varies with EXEC,
        // but <=4 outstanding non-W ops -> wait 4 is safe and counted)
        S_WAIT_VM(4); SBAR0();
        mfmaPhase(cur);                         // contains S_WAIT_LG(0)
        SBAR0();
        __builtin_amdgcn_s_barrier();           // raw: no vmem drain
        SBAR0();
        cur  = (cur == 2)  ? 0 : cur + 1;
        nxt2 = (nxt2 == 2) ? 0 : nxt2 + 1;
    }
    // ---- peeled s = SG-2 ----
    loadW(wb);  wb += WSTP;
    SBAR0();
    S_WAIT_VM(0); SBAR0();                      // everything retired
    mfmaPhase(cur);
    SBAR0();
    __builtin_amdgcn_s_barrier();
    SBAR0();
    cur = (cur == 2) ? 0 : cur + 1;
    // ---- peeled s = SG-1 ----
    loadW(wb);
    SBAR0();
    S_WAIT_VM(0); SBAR0();
    mfmaPhase(cur);

    // ---- fused BN statsA: per-block partial sum/sumsq per channel ----
    __syncthreads();
    float* smf = (float*)ldsA;             // overlay [WM][COUT][2]
#pragma unroll
    for (int n = 0; n < FN; ++n) {
        float s1 = 0.f, s2 = 0.f;
#pragma unroll
        for (int m = 0; m < FM; ++m)
#pragma unroll
            for (int q = 0; q < 4; ++q) {
                float v = acc[m][n][q];
                s1 += v; s2 += v * v;
            }
        s1 += __shfl_xor(s1, 16); s1 += __shfl_xor(s1, 32);
        s2 += __shfl_xor(s2, 16); s2 += __shfl_xor(s2, 32);
        if (lane < 16) {
            int col = wn * (FN * 16) + n * 16 + lr;
            smf[(wm * COUT + col) * 2 + 0] = s1;
            smf[(wm * COUT + col) * 2 + 1] = s2;
        }
    }
    __syncthreads();
    if (tid < 2 * COUT) {
        int z = tid / COUT, cc = tid % COUT;
        float v = 0.f;
#pragma unroll
        for (int w = 0; w < WM; ++w) v += smf[(w * COUT + cc) * 2 + z];
        part[(size_t)blockIdx.x * (2 * COUT) + z * COUT + cc] = v;
    }

    // ---- store h (bf16): D layout col=lane&15, row=(lane>>4)*4+q ----
#pragma unroll
    for (int m = 0; m < FM; ++m) {
#pragma unroll
        for (int q = 0; q < 4; ++q) {
            int row = row0 + wm * (FM * 16) + m * 16 + lk * 4 + q;
            if (row < NVOX) {
#pragma unroll
                for (int n = 0; n < FN; ++n) {
                    int col = wn * (FN * 16) + n * 16 + lr;
                    hout[(size_t)row * COUT + col] = f2bf(acc[m][n][q]);
                }
            }
        }
    }
}

// ---------------------------------------------------------------------------
// BN stats reduce: sum partials over NBLK blocks, emit scale/shift
// ---------------------------------------------------------------------------
template<int COUT>
__global__ __launch_bounds__(256) void bn_statsB(
    const float* __restrict__ part, const float* __restrict__ g,
    const float* __restrict__ bv, float* __restrict__ ss)
{
    const int c = blockIdx.x;
    const int t = threadIdx.x;
    float s1 = 0.f, s2 = 0.f;
    for (int b = t; b < NBLK; b += 256) {
        s1 += part[(size_t)b * 2 * COUT + c];
        s2 += part[(size_t)b * 2 * COUT + COUT + c];
    }
#pragma unroll
    for (int d = 1; d < 64; d <<= 1) {
        s1 += __shfl_xor(s1, d);
        s2 += __shfl_xor(s2, d);
    }
    __shared__ float rs[8];
    int w = t >> 6;
    if ((t & 63) == 0) { rs[w] = s1; rs[4 + w] = s2; }
    __syncthreads();
    if (t == 0) {
        s1 = rs[0] + rs[1] + rs[2] + rs[3];
        s2 = rs[4] + rs[5] + rs[6] + rs[7];
        float mu  = s1 * (1.0f / NVOX);
        float var = s2 * (1.0f / NVOX) - mu * mu;
        float sc  = g[c] * rsqrtf(var + 1e-5f);
        ss[c] = sc;
        ss[COUT + c] = bv[c] - mu * sc;
    }
}

// ---------------------------------------------------------------------------
// apply BN + ReLU in place (bf16), vec8
// ---------------------------------------------------------------------------
template<int COUT>
__global__ __launch_bounds__(256) void bn_apply_relu(
    u16* __restrict__ h, const float* __restrict__ ss)
{
    int t = blockIdx.x * 256 + threadIdx.x;   // < NVOX*COUT/8
    int c0 = (t * 8) % COUT;
    ushort8v v = *(ushort8v*)(h + (size_t)t * 8);
#pragma unroll
    for (int j = 0; j < 8; ++j) {
        float f = bf2f(v[j]);
        f = fmaxf(f * ss[c0 + j] + ss[COUT + c0 + j], 0.f);
        v[j] = f2bf(f);
    }
    *(ushort8v*)(h + (size_t)t * 8) = v;
}

// ---------------------------------------------------------------------------
// final: out = relu(scale2*h2 + shift2 + x), f32 out, vec8
// ---------------------------------------------------------------------------
__global__ __launch_bounds__(256) void final_kernel(
    const u16* __restrict__ h2, const float* __restrict__ x,
    const float* __restrict__ ss, float* __restrict__ out)
{
    int t = blockIdx.x * 256 + threadIdx.x;   // < NVOX*96/8
    int c0 = (t * 8) % 96;
    ushort8v v = *(const ushort8v*)(h2 + (size_t)t * 8);
    float4 x0 = *(const float4*)(x + (size_t)t * 8);
    float4 x1 = *(const float4*)(x + (size_t)t * 8 + 4);
    float xs[8] = {x0.x, x0.y, x0.z, x0.w, x1.x, x1.y, x1.z, x1.w};
    float o[8];
#pragma unroll
    for (int j = 0; j < 8; ++j) {
        float f = bf2f(v[j]) * ss[c0 + j] + ss[96 + c0 + j] + xs[j];
        o[j] = fmaxf(f, 0.f);
    }
    *(float4*)(out + (size_t)t * 8)     = (float4){o[0], o[1], o[2], o[3]};
    *(float4*)(out + (size_t)t * 8 + 4) = (float4){o[4], o[5], o[6], o[7]};
}

// ---------------------------------------------------------------------------
extern "C" void kernel_launch(void* const* d_in, const int* in_sizes, int n_in,
                              void* d_out, int out_size, void* d_ws, size_t ws_size,
                              hipStream_t stream)
{
    const float* x    = (const float*)d_in[0];
    const int*   idx  = (const int*)d_in[1];
    const int*   mask = (const int*)d_in[2];
    const float* W1   = (const float*)d_in[3];
    const float* g1   = (const float*)d_in[4];
    const float* b1   = (const float*)d_in[5];
    const float* W2   = (const float*)d_in[6];
    const float* g2   = (const float*)d_in[7];
    const float* b2   = (const float*)d_in[8];

    unsigned char* ws = (unsigned char*)d_ws;
    u16*  xb    = (u16*)ws;                          // 38,400,000 B
    u16*  w1t   = (u16*)(ws + 38400000);             //    995,328 B
    u16*  w2t   = (u16*)(ws + 39395328);             //    995,328 B
    u16*  h2    = (u16*)(ws + 40390656);             // 38,400,000 B
    float* part = (float*)(ws + 78790656);           //  2,400,768 B
    float* ss1  = (float*)(ws + 81191424);           //      1,536 B
    float* ss2  = (float*)(ws + 81192960);           //        768 B
    float* zbuf = (float*)(ws + 81193728);           //        256 B
    int*  lsrcG = (int*)(ws + 81193984);             // 21,606,912 B

    u16* h = (u16*)d_out;         // reuse d_out (76.8MB) as [N][192] bf16

    prep_kernel<<<19236, 256, 0, stream>>>(x, W1, W2, xb, w1t, w2t, zbuf);
    lsrc_kernel<<<dim3(782, 27), 256, 0, stream>>>(idx, mask, lsrcG);

    // conv1: COUT=192, 2m x 4n waves (FM=4, FN=3), K=96 per offset
    conv_mfma<192, 4, 1><<<NBLK, 512, 0, stream>>>(xb, lsrcG, w1t, zbuf, h, part);
    bn_statsB<192><<<192, 256, 0, stream>>>(part, g1, b1, ss1);
    bn_apply_relu<192><<<18750, 256, 0, stream>>>(h, ss1);

    // conv2: COUT=96, 4m x 2n waves (FM=2, FN=3), K=192 in two 96-phases
    conv_mfma<96, 2, 2><<<NBLK, 512, 0, stream>>>(h, lsrcG, w2t, zbuf, h2, part);
    bn_statsB<96><<<96, 256, 0, stream>>>(part, g2, b2, ss2);
    final_kernel<<<9375, 256, 0, stream>>>(h2, x, ss2, (float*)d_out);
}